// Round 13
// baseline (214.458 us; speedup 1.0000x reference)
//
#include <hip/hip_runtime.h>
#include <cstddef>

#define NN 100000
#define NE 640000
#define NB_SCAN 391   // ceil(NN/256)
#define NTILE 1563    // ceil(NN/64)

typedef short  short8   __attribute__((ext_vector_type(8)));
typedef float  f32x4    __attribute__((ext_vector_type(4)));
typedef ushort ushort4v __attribute__((ext_vector_type(4)));

__device__ __forceinline__ short f2bf(float f) {   // RNE f32->bf16
    union { float f; unsigned u; } v; v.f = f;
    unsigned r = (v.u + 0x7fffu + ((v.u >> 16) & 1u)) >> 16;
    return (short)r;
}

// K-1 (merged): blocks 0..195 zero count+cursor; blocks 196..259 compute
// fused first-layer weights EVW1 = evW@W1 (bf16 [n][j]) and EVB1 = evb@W1.
__global__ __launch_bounds__(256) void k_init(
    int4* __restrict__ zp, const float* __restrict__ evW,
    const float* __restrict__ evb, const float* __restrict__ W1,
    ushort* __restrict__ EVW1t, float* __restrict__ EVB1)
{
    const int b = blockIdx.x;
    if (b < 196) {
        const int i = b * 256 + threadIdx.x;        // 50176 >= 50000
        if (i < 50000) zp[i] = make_int4(0, 0, 0, 0);
        return;
    }
    if (threadIdx.x >= 128) return;
    const int j = b - 196;        // 0..63
    const int n = threadIdx.x;    // 0..127
    float acc = 0.f;
    #pragma unroll 8
    for (int c = 0; c < 128; ++c)
        acc = fmaf(evW[j * 128 + c], W1[c * 128 + n], acc);
    EVW1t[n * 64 + j] = (ushort)f2bf(acc);
    if (j == 0) {
        float ab = 0.f;
        #pragma unroll 8
        for (int c = 0; c < 128; ++c)
            ab = fmaf(evb[c], W1[c * 128 + n], ab);
        EVB1[n] = ab;
    }
}

// K0: W2 bf16-transpose + in-degree histogram.
__global__ __launch_bounds__(256) void k_pre(
    const float* __restrict__ W2, const int* __restrict__ dst_idx,
    int* __restrict__ count, ushort* __restrict__ W2t)
{
    const int gid = blockIdx.x * 256 + threadIdx.x;   // grid 2500 -> gid < NE
    if (gid < 16384) {
        const int n = gid >> 7, k = gid & 127;
        W2t[gid] = (ushort)f2bf(W2[k * 128 + n]);
    }
    atomicAdd(&count[dst_idx[gid]], 1);               // 2500*256 == NE exactly
}

// Scan A: per-block sums
__global__ __launch_bounds__(256) void k_scan_bsum(
    const int* __restrict__ count, int* __restrict__ bsum)
{
    __shared__ int s[256];
    const int t = threadIdx.x, i = blockIdx.x * 256 + t;
    s[t] = (i < NN) ? count[i] : 0;
    __syncthreads();
    for (int off = 128; off; off >>= 1) { if (t < off) s[t] += s[t + off]; __syncthreads(); }
    if (t == 0) bsum[blockIdx.x] = s[0];
}

// Scan B (merged): block prefix over bsum + in-block exclusive scan -> rowptr
__global__ __launch_bounds__(256) void k_scan_final(
    const int* __restrict__ count, const int* __restrict__ bsum,
    int* __restrict__ rowptr)
{
    __shared__ int s[256];
    __shared__ int red[4];
    const int t = threadIdx.x, i = blockIdx.x * 256 + t;
    const int v = (i < NN) ? count[i] : 0;
    s[t] = v;

    int part = 0;
    for (int b = t; b < blockIdx.x; b += 256) part += bsum[b];
    #pragma unroll
    for (int off = 32; off; off >>= 1) part += __shfl_xor(part, off);
    if ((t & 63) == 0) red[t >> 6] = part;
    __syncthreads();
    const int boff = red[0] + red[1] + red[2] + red[3];

    for (int off = 1; off < 256; off <<= 1) {
        const int x = (t >= off) ? s[t - off] : 0;
        __syncthreads();
        s[t] += x;
        __syncthreads();
    }
    if (i < NN) rowptr[i] = boff + s[t] - v;
    if (blockIdx.x == NB_SCAN - 1 && t == 255) rowptr[NN] = boff + s[255];
}

// K2: build permutation grouping edges by dst (CSR)
__global__ __launch_bounds__(256) void k_permute(
    const int* __restrict__ dst_idx, const int* __restrict__ rowptr,
    int* cursor, int* __restrict__ perm)
{
    const int e = blockIdx.x * 256 + threadIdx.x;     // grid 2500 exact
    const int dd = dst_idx[e];
    perm[rowptr[dd] + atomicAdd(&cursor[dd], 1)] = e;
}

// K3: gather + online segment softmax + aggregation.
// DIAGNOSTIC: rep=2 (idempotent re-run) to lift per-dispatch duration above
// the harness poison-fills so rocprof top-5 shows this kernel WITH counters.
__global__ __launch_bounds__(256, 8) void k_agg_gather(
    const float* __restrict__ ef, const float* __restrict__ attn_W,
    const int* __restrict__ perm, const int* __restrict__ rowptr,
    ushort* __restrict__ agg, float* __restrict__ msum)
{
    const int t  = threadIdx.x;
    const int sl = t & 15;
    const int n  = blockIdx.x * 16 + (t >> 4);   // grid 6250 -> exact
    const int beg = rowptr[n], end = rowptr[n + 1];

    float4 wl;   // mean_h attn_W rows 128+sl*4 .. +3
    {
        const float4 r0 = *reinterpret_cast<const float4*>(attn_W + (128 + sl * 4 + 0) * 4);
        const float4 r1 = *reinterpret_cast<const float4*>(attn_W + (128 + sl * 4 + 1) * 4);
        const float4 r2 = *reinterpret_cast<const float4*>(attn_W + (128 + sl * 4 + 2) * 4);
        const float4 r3 = *reinterpret_cast<const float4*>(attn_W + (128 + sl * 4 + 3) * 4);
        wl.x = 0.25f * (r0.x + r0.y + r0.z + r0.w);
        wl.y = 0.25f * (r1.x + r1.y + r1.z + r1.w);
        wl.z = 0.25f * (r2.x + r2.y + r2.z + r2.w);
        wl.w = 0.25f * (r3.x + r3.y + r3.z + r3.w);
    }

    for (int rep = 0; rep < 2; ++rep) {
        float minit = -3.0e38f;
        asm volatile("" : "+v"(minit));          // LICM breaker: body not rep-invariant
        float m  = minit;
        float se = 0.f;
        f32x4 acc = {0.f, 0.f, 0.f, 0.f};

        for (int i = beg; i < end; i += 6) {
            int pe[6];
            #pragma unroll
            for (int j = 0; j < 6; ++j)
                pe[j] = perm[(i + j < end) ? (i + j) : beg];
            float4 v[6];
            #pragma unroll
            for (int j = 0; j < 6; ++j)
                v[j] = *reinterpret_cast<const float4*>(ef + (size_t)pe[j] * 64 + sl * 4);
            float sc[6];
            #pragma unroll
            for (int j = 0; j < 6; ++j) {
                float x = v[j].x * wl.x + v[j].y * wl.y + v[j].z * wl.z + v[j].w * wl.w;
                #pragma unroll
                for (int off = 8; off; off >>= 1) x += __shfl_xor(x, off, 16);
                sc[j] = (i + j < end) ? x : -3.0e38f;
            }
            float bm = m;
            #pragma unroll
            for (int j = 0; j < 6; ++j) bm = fmaxf(bm, sc[j]);
            const float r = __expf(m - bm);
            acc[0] *= r; acc[1] *= r; acc[2] *= r; acc[3] *= r; se *= r;
            m = bm;
            #pragma unroll
            for (int j = 0; j < 6; ++j) {
                const float w = __expf(sc[j] - m);
                acc[0] = fmaf(w, v[j].x, acc[0]);
                acc[1] = fmaf(w, v[j].y, acc[1]);
                acc[2] = fmaf(w, v[j].z, acc[2]);
                acc[3] = fmaf(w, v[j].w, acc[3]);
                se += w;
            }
        }

        ushort4v o;
        o[0] = (ushort)f2bf(acc[0]); o[1] = (ushort)f2bf(acc[1]);
        o[2] = (ushort)f2bf(acc[2]); o[3] = (ushort)f2bf(acc[3]);
        *reinterpret_cast<ushort4v*>(agg + (size_t)n * 64 + sl * 4) = o;
        if (sl == 0) msum[n] = se;
    }
}

// K5: single-pass MLP. DIAGNOSTIC: rep=3 (idempotent re-run) for counters.
__global__ __launch_bounds__(256, 2) void k_mega(
    const ushort* __restrict__ agg, const float* __restrict__ msum,
    const ushort* __restrict__ EVW1t, const float* __restrict__ EVB1,
    const float* __restrict__ b1, const ushort* __restrict__ W2t,
    const float* __restrict__ b2, const float* __restrict__ nf,
    float* __restrict__ out)
{
    __shared__ ushort wev[128 * 64];     // 16 KB EVW1 rows, swizzled
    __shared__ ushort ww2[128 * 128];    // 32 KB W2 rows, swizzled
    __shared__ ushort tl[4][16][136];    // 17 KB per-wave h1 staging

    const int tid  = threadIdx.x;
    const int wid  = tid >> 6;
    const int lane = tid & 63;
    const int r    = lane & 15;
    const int g    = lane >> 4;

    for (int c = tid; c < 1024; c += 256) {        // EVW1: 1024 x short8
        const int n = c >> 3, k8 = c & 7;
        *reinterpret_cast<short8*>(&wev[n * 64 + ((k8 ^ (n & 7)) * 8)]) =
            *reinterpret_cast<const short8*>(EVW1t + n * 64 + k8 * 8);
    }
    for (int c = tid; c < 2048; c += 256) {        // W2: 2048 x short8
        const int n = c >> 4, k8 = c & 15;
        *reinterpret_cast<short8*>(&ww2[n * 128 + ((k8 ^ (n & 7)) * 8)]) =
            *reinterpret_cast<const short8*>(W2t + n * 128 + k8 * 8);
    }
    __syncthreads();

    float evb1c[8], b1c[8], b2c[8];
    #pragma unroll
    for (int nt = 0; nt < 8; ++nt) {
        evb1c[nt] = EVB1[nt * 16 + r];
        b1c[nt]   = b1[nt * 16 + r];
        b2c[nt]   = b2[nt * 16 + r];
    }

    for (int rep = 0; rep < 3; ++rep) {
        float eps = 1e-6f;
        asm volatile("" : "+v"(eps));              // LICM breaker
        for (int bt = blockIdx.x; bt < NTILE; bt += gridDim.x) {
            const int n0 = bt * 64 + wid * 16;
            if (n0 >= NN) continue;                // no syncs in loop -> safe

            const short8 aev0 = *reinterpret_cast<const short8*>(agg + (size_t)(n0 + r) * 64 + g * 8);
            const short8 aev1 = *reinterpret_cast<const short8*>(agg + (size_t)(n0 + r) * 64 + 32 + g * 8);
            float cf[4], cb[4];
            #pragma unroll
            for (int i = 0; i < 4; ++i) {
                const float s = msum[n0 + g * 4 + i];
                const float c = 1.f / (s + eps);
                cf[i] = c; cb[i] = s * c;
            }

            #pragma unroll
            for (int nt = 0; nt < 8; ++nt) {
                const int row = nt * 16 + r;
                const short8 w0 = *reinterpret_cast<const short8*>(
                    &wev[row * 64 + (((0 + g) ^ (r & 7)) * 8)]);
                const short8 w1 = *reinterpret_cast<const short8*>(
                    &wev[row * 64 + (((4 + g) ^ (r & 7)) * 8)]);
                f32x4 acc = {0.f, 0.f, 0.f, 0.f};
                acc = __builtin_amdgcn_mfma_f32_16x16x32_bf16(aev0, w0, acc, 0, 0, 0);
                acc = __builtin_amdgcn_mfma_f32_16x16x32_bf16(aev1, w1, acc, 0, 0, 0);
                #pragma unroll
                for (int i = 0; i < 4; ++i) {
                    const float h = fmaxf(cf[i] * acc[i] + cb[i] * evb1c[nt] + b1c[nt], 0.f);
                    tl[wid][g * 4 + i][nt * 16 + r] = (ushort)f2bf(h);
                }
            }
            asm volatile("s_waitcnt lgkmcnt(0)" ::: "memory");   // h1 writes landed

            short8 a2[4];
            #pragma unroll
            for (int t = 0; t < 4; ++t)
                a2[t] = *reinterpret_cast<const short8*>(&tl[wid][r][t * 32 + g * 8]);
            asm volatile("s_waitcnt lgkmcnt(0)" ::: "memory");   // reads done before overwrite

            #pragma unroll
            for (int nt = 0; nt < 8; ++nt) {
                f32x4 acc = {0.f, 0.f, 0.f, 0.f};
                #pragma unroll
                for (int t = 0; t < 4; ++t) {
                    const short8 w = *reinterpret_cast<const short8*>(
                        &ww2[(nt * 16 + r) * 128 + (((t * 4 + g) ^ (r & 7)) * 8)]);
                    acc = __builtin_amdgcn_mfma_f32_16x16x32_bf16(a2[t], w, acc, 0, 0, 0);
                }
                #pragma unroll
                for (int i = 0; i < 4; ++i) {
                    const size_t idx = (size_t)(n0 + g * 4 + i) * 128 + nt * 16 + r;
                    out[idx] = nf[idx] + acc[i] + b2c[nt];
                }
            }
        }
    }
}

extern "C" void kernel_launch(void* const* d_in, const int* in_sizes, int n_in,
                              void* d_out, int out_size, void* d_ws, size_t ws_size,
                              hipStream_t stream)
{
    const float* nf     = (const float*)d_in[0];
    const float* ef     = (const float*)d_in[1];
    const float* attn_W = (const float*)d_in[2];
    const float* evW    = (const float*)d_in[4];
    const float* evb    = (const float*)d_in[5];
    const float* W1     = (const float*)d_in[6];
    const float* b1     = (const float*)d_in[7];
    const float* W2     = (const float*)d_in[8];
    const float* b2     = (const float*)d_in[9];
    const int*   eidx   = (const int*)d_in[10];
    const int*   dst    = eidx + NE;
    float* out = (float*)d_out;

    char* ws = (char*)d_ws;
    int*    count  = (int*)   (ws + 0);          //   400,000 } contiguous:
    int*    cursor = (int*)   (ws + 400000);     //   400,000 } zeroed by k_init
    int*    rowptr = (int*)   (ws + 800000);     //   400,004 (pad -> 1,200,128)
    float*  msum   = (float*) (ws + 1200128);    //   400,000
    int*    perm   = (int*)   (ws + 1600128);    // 2,560,000
    ushort* agg    = (ushort*)(ws + 4160128);    // 12,800,000
    ushort* W2t    = (ushort*)(ws + 16960128);   //    32,768
    ushort* EVW1t  = (ushort*)(ws + 16992896);   //    16,384
    float*  EVB1   = (float*) (ws + 17009280);   //       512
    int*    bsum   = (int*)   (ws + 17009792);   //     1,664  (total ~17.0 MB)

    k_init       <<<260,  256, 0, stream>>>((int4*)count, evW, evb, W1, EVW1t, EVB1);
    k_pre        <<<2500, 256, 0, stream>>>(W2, dst, count, W2t);
    k_scan_bsum  <<<NB_SCAN, 256, 0, stream>>>(count, bsum);
    k_scan_final <<<NB_SCAN, 256, 0, stream>>>(count, bsum, rowptr);
    k_permute    <<<2500, 256, 0, stream>>>(dst, rowptr, cursor, perm);
    k_agg_gather <<<6250, 256, 0, stream>>>(ef, attn_W, perm, rowptr, agg, msum);
    k_mega       <<<521,  256, 0, stream>>>(agg, msum, EVW1t, EVB1, b1, W2t, b2, nf, out);
}

// Round 14
// 184.638 us; speedup vs baseline: 1.1615x; 1.1615x over previous
//
#include <hip/hip_runtime.h>
#include <cstddef>

#define NN 100000
#define NE 640000
#define NB_SCAN 391   // ceil(NN/256)
#define NTILE 1563    // ceil(NN/64)

typedef short  short8   __attribute__((ext_vector_type(8)));
typedef float  f32x4    __attribute__((ext_vector_type(4)));
typedef ushort ushort4v __attribute__((ext_vector_type(4)));

__device__ __forceinline__ short f2bf(float f) {   // RNE f32->bf16
    union { float f; unsigned u; } v; v.f = f;
    unsigned r = (v.u + 0x7fffu + ((v.u >> 16) & 1u)) >> 16;
    return (short)r;
}

// K-1 (merged): blocks 0..195 zero count+cursor; blocks 196..259 compute
// fused first-layer weights EVW1 = evW@W1 (bf16 [n][j]) and EVB1 = evb@W1.
__global__ __launch_bounds__(256) void k_init(
    int4* __restrict__ zp, const float* __restrict__ evW,
    const float* __restrict__ evb, const float* __restrict__ W1,
    ushort* __restrict__ EVW1t, float* __restrict__ EVB1)
{
    const int b = blockIdx.x;
    if (b < 196) {
        const int i = b * 256 + threadIdx.x;        // 50176 >= 50000
        if (i < 50000) zp[i] = make_int4(0, 0, 0, 0);
        return;
    }
    if (threadIdx.x >= 128) return;
    const int j = b - 196;        // 0..63
    const int n = threadIdx.x;    // 0..127
    float acc = 0.f;
    #pragma unroll 8
    for (int c = 0; c < 128; ++c)
        acc = fmaf(evW[j * 128 + c], W1[c * 128 + n], acc);
    EVW1t[n * 64 + j] = (ushort)f2bf(acc);
    if (j == 0) {
        float ab = 0.f;
        #pragma unroll 8
        for (int c = 0; c < 128; ++c)
            ab = fmaf(evb[c], W1[c * 128 + n], ab);
        EVB1[n] = ab;
    }
}

// K0: W2 bf16-transpose + in-degree histogram.
__global__ __launch_bounds__(256) void k_pre(
    const float* __restrict__ W2, const int* __restrict__ dst_idx,
    int* __restrict__ count, ushort* __restrict__ W2t)
{
    const int gid = blockIdx.x * 256 + threadIdx.x;   // grid 2500 -> gid < NE
    if (gid < 16384) {
        const int n = gid >> 7, k = gid & 127;
        W2t[gid] = (ushort)f2bf(W2[k * 128 + n]);
    }
    atomicAdd(&count[dst_idx[gid]], 1);               // 2500*256 == NE exactly
}

// Scan A: per-block sums
__global__ __launch_bounds__(256) void k_scan_bsum(
    const int* __restrict__ count, int* __restrict__ bsum)
{
    __shared__ int s[256];
    const int t = threadIdx.x, i = blockIdx.x * 256 + t;
    s[t] = (i < NN) ? count[i] : 0;
    __syncthreads();
    for (int off = 128; off; off >>= 1) { if (t < off) s[t] += s[t + off]; __syncthreads(); }
    if (t == 0) bsum[blockIdx.x] = s[0];
}

// Scan B (merged): block prefix over bsum + in-block exclusive scan -> rowptr
__global__ __launch_bounds__(256) void k_scan_final(
    const int* __restrict__ count, const int* __restrict__ bsum,
    int* __restrict__ rowptr)
{
    __shared__ int s[256];
    __shared__ int red[4];
    const int t = threadIdx.x, i = blockIdx.x * 256 + t;
    const int v = (i < NN) ? count[i] : 0;
    s[t] = v;

    int part = 0;
    for (int b = t; b < blockIdx.x; b += 256) part += bsum[b];
    #pragma unroll
    for (int off = 32; off; off >>= 1) part += __shfl_xor(part, off);
    if ((t & 63) == 0) red[t >> 6] = part;
    __syncthreads();
    const int boff = red[0] + red[1] + red[2] + red[3];

    for (int off = 1; off < 256; off <<= 1) {
        const int x = (t >= off) ? s[t - off] : 0;
        __syncthreads();
        s[t] += x;
        __syncthreads();
    }
    if (i < NN) rowptr[i] = boff + s[t] - v;
    if (blockIdx.x == NB_SCAN - 1 && t == 255) rowptr[NN] = boff + s[255];
}

// K2: build permutation grouping edges by dst (CSR)
__global__ __launch_bounds__(256) void k_permute(
    const int* __restrict__ dst_idx, const int* __restrict__ rowptr,
    int* cursor, int* __restrict__ perm)
{
    const int e = blockIdx.x * 256 + threadIdx.x;     // grid 2500 exact
    const int dd = dst_idx[e];
    perm[rowptr[dd] + atomicAdd(&cursor[dd], 1)] = e;
}

// K3: gather + online segment softmax + aggregation (R12 version; measured
// near the random-256B-gather HBM limit -- L3-warm rerun was 5x faster).
__global__ __launch_bounds__(256, 8) void k_agg_gather(
    const float* __restrict__ ef, const float* __restrict__ attn_W,
    const int* __restrict__ perm, const int* __restrict__ rowptr,
    ushort* __restrict__ agg, float* __restrict__ msum)
{
    const int t  = threadIdx.x;
    const int sl = t & 15;
    const int n  = blockIdx.x * 16 + (t >> 4);   // grid 6250 -> exact
    const int beg = rowptr[n], end = rowptr[n + 1];

    float4 wl;   // mean_h attn_W rows 128+sl*4 .. +3
    {
        const float4 r0 = *reinterpret_cast<const float4*>(attn_W + (128 + sl * 4 + 0) * 4);
        const float4 r1 = *reinterpret_cast<const float4*>(attn_W + (128 + sl * 4 + 1) * 4);
        const float4 r2 = *reinterpret_cast<const float4*>(attn_W + (128 + sl * 4 + 2) * 4);
        const float4 r3 = *reinterpret_cast<const float4*>(attn_W + (128 + sl * 4 + 3) * 4);
        wl.x = 0.25f * (r0.x + r0.y + r0.z + r0.w);
        wl.y = 0.25f * (r1.x + r1.y + r1.z + r1.w);
        wl.z = 0.25f * (r2.x + r2.y + r2.z + r2.w);
        wl.w = 0.25f * (r3.x + r3.y + r3.z + r3.w);
    }

    float m  = -3.0e38f;
    float se = 0.f;
    f32x4 acc = {0.f, 0.f, 0.f, 0.f};

    for (int i = beg; i < end; i += 6) {
        int pe[6];
        #pragma unroll
        for (int j = 0; j < 6; ++j)
            pe[j] = perm[(i + j < end) ? (i + j) : beg];
        float4 v[6];
        #pragma unroll
        for (int j = 0; j < 6; ++j)
            v[j] = *reinterpret_cast<const float4*>(ef + (size_t)pe[j] * 64 + sl * 4);
        float sc[6];
        #pragma unroll
        for (int j = 0; j < 6; ++j) {
            float x = v[j].x * wl.x + v[j].y * wl.y + v[j].z * wl.z + v[j].w * wl.w;
            #pragma unroll
            for (int off = 8; off; off >>= 1) x += __shfl_xor(x, off, 16);
            sc[j] = (i + j < end) ? x : -3.0e38f;
        }
        float bm = m;
        #pragma unroll
        for (int j = 0; j < 6; ++j) bm = fmaxf(bm, sc[j]);
        const float r = __expf(m - bm);
        acc[0] *= r; acc[1] *= r; acc[2] *= r; acc[3] *= r; se *= r;
        m = bm;
        #pragma unroll
        for (int j = 0; j < 6; ++j) {
            const float w = __expf(sc[j] - m);
            acc[0] = fmaf(w, v[j].x, acc[0]);
            acc[1] = fmaf(w, v[j].y, acc[1]);
            acc[2] = fmaf(w, v[j].z, acc[2]);
            acc[3] = fmaf(w, v[j].w, acc[3]);
            se += w;
        }
    }

    ushort4v o;
    o[0] = (ushort)f2bf(acc[0]); o[1] = (ushort)f2bf(acc[1]);
    o[2] = (ushort)f2bf(acc[2]); o[3] = (ushort)f2bf(acc[3]);
    *reinterpret_cast<ushort4v*>(agg + (size_t)n * 64 + sl * 4) = o;
    if (sl == 0) msum[n] = se;
}

// K5 v6: occupancy fix (R13 counters: Occ 15.5%, nothing else saturated).
// W2 fragments read DIRECTLY from global (32 KB, L2/L3-hot; pattern validated
// in R2-R8). LDS = wev 16 KB + tl 17.4 KB = 33.4 KB -> 4 blocks/CU.
__global__ __launch_bounds__(256, 4) void k_mega(
    const ushort* __restrict__ agg, const float* __restrict__ msum,
    const ushort* __restrict__ EVW1t, const float* __restrict__ EVB1,
    const float* __restrict__ b1, const ushort* __restrict__ W2t,
    const float* __restrict__ b2, const float* __restrict__ nf,
    float* __restrict__ out)
{
    __shared__ ushort wev[128 * 64];     // 16 KB EVW1 rows, swizzled
    __shared__ ushort tl[4][16][136];    // 17.4 KB per-wave h1 staging

    const int tid  = threadIdx.x;
    const int wid  = tid >> 6;
    const int lane = tid & 63;
    const int r    = lane & 15;
    const int g    = lane >> 4;

    for (int c = tid; c < 1024; c += 256) {        // EVW1: 1024 x short8
        const int n = c >> 3, k8 = c & 7;
        *reinterpret_cast<short8*>(&wev[n * 64 + ((k8 ^ (n & 7)) * 8)]) =
            *reinterpret_cast<const short8*>(EVW1t + n * 64 + k8 * 8);
    }
    __syncthreads();

    float evb1c[8], b1c[8], b2c[8];
    #pragma unroll
    for (int nt = 0; nt < 8; ++nt) {
        evb1c[nt] = EVB1[nt * 16 + r];
        b1c[nt]   = b1[nt * 16 + r];
        b2c[nt]   = b2[nt * 16 + r];
    }

    for (int bt = blockIdx.x; bt < NTILE; bt += gridDim.x) {
        const int n0 = bt * 64 + wid * 16;
        if (n0 >= NN) continue;                    // no syncs in loop -> safe

        const short8 aev0 = *reinterpret_cast<const short8*>(agg + (size_t)(n0 + r) * 64 + g * 8);
        const short8 aev1 = *reinterpret_cast<const short8*>(agg + (size_t)(n0 + r) * 64 + 32 + g * 8);
        float cf[4], cb[4];
        #pragma unroll
        for (int i = 0; i < 4; ++i) {
            const float s = msum[n0 + g * 4 + i];
            const float c = 1.f / (s + 1e-6f);
            cf[i] = c; cb[i] = s * c;
        }

        // ---- fused ev+L1 GEMM (K=64) + relu -> h1 (bf16, wave-private LDS) ----
        #pragma unroll
        for (int nt = 0; nt < 8; ++nt) {
            const int row = nt * 16 + r;
            const short8 w0 = *reinterpret_cast<const short8*>(
                &wev[row * 64 + (((0 + g) ^ (r & 7)) * 8)]);
            const short8 w1 = *reinterpret_cast<const short8*>(
                &wev[row * 64 + (((4 + g) ^ (r & 7)) * 8)]);
            f32x4 acc = {0.f, 0.f, 0.f, 0.f};
            acc = __builtin_amdgcn_mfma_f32_16x16x32_bf16(aev0, w0, acc, 0, 0, 0);
            acc = __builtin_amdgcn_mfma_f32_16x16x32_bf16(aev1, w1, acc, 0, 0, 0);
            #pragma unroll
            for (int i = 0; i < 4; ++i) {
                const float h = fmaxf(cf[i] * acc[i] + cb[i] * evb1c[nt] + b1c[nt], 0.f);
                tl[wid][g * 4 + i][nt * 16 + r] = (ushort)f2bf(h);
            }
        }
        asm volatile("s_waitcnt lgkmcnt(0)" ::: "memory");   // h1 writes landed

        short8 a2[4];
        #pragma unroll
        for (int t = 0; t < 4; ++t)
            a2[t] = *reinterpret_cast<const short8*>(&tl[wid][r][t * 32 + g * 8]);
        asm volatile("s_waitcnt lgkmcnt(0)" ::: "memory");   // reads done before next overwrite

        // ---- GEMM2 + bias + residual; W2 B-frags from global (L2-hot) ----
        #pragma unroll
        for (int nt = 0; nt < 8; ++nt) {
            f32x4 acc = {0.f, 0.f, 0.f, 0.f};
            #pragma unroll
            for (int t = 0; t < 4; ++t) {
                const short8 w = *reinterpret_cast<const short8*>(
                    W2t + (size_t)(nt * 16 + r) * 128 + t * 32 + g * 8);
                acc = __builtin_amdgcn_mfma_f32_16x16x32_bf16(a2[t], w, acc, 0, 0, 0);
            }
            #pragma unroll
            for (int i = 0; i < 4; ++i) {
                const size_t idx = (size_t)(n0 + g * 4 + i) * 128 + nt * 16 + r;
                out[idx] = nf[idx] + acc[i] + b2c[nt];
            }
        }
    }
}

extern "C" void kernel_launch(void* const* d_in, const int* in_sizes, int n_in,
                              void* d_out, int out_size, void* d_ws, size_t ws_size,
                              hipStream_t stream)
{
    const float* nf     = (const float*)d_in[0];
    const float* ef     = (const float*)d_in[1];
    const float* attn_W = (const float*)d_in[2];
    const float* evW    = (const float*)d_in[4];
    const float* evb    = (const float*)d_in[5];
    const float* W1     = (const float*)d_in[6];
    const float* b1     = (const float*)d_in[7];
    const float* W2     = (const float*)d_in[8];
    const float* b2     = (const float*)d_in[9];
    const int*   eidx   = (const int*)d_in[10];
    const int*   dst    = eidx + NE;
    float* out = (float*)d_out;

    char* ws = (char*)d_ws;
    int*    count  = (int*)   (ws + 0);          //   400,000 } contiguous:
    int*    cursor = (int*)   (ws + 400000);     //   400,000 } zeroed by k_init
    int*    rowptr = (int*)   (ws + 800000);     //   400,004 (pad -> 1,200,128)
    float*  msum   = (float*) (ws + 1200128);    //   400,000
    int*    perm   = (int*)   (ws + 1600128);    // 2,560,000
    ushort* agg    = (ushort*)(ws + 4160128);    // 12,800,000
    ushort* W2t    = (ushort*)(ws + 16960128);   //    32,768
    ushort* EVW1t  = (ushort*)(ws + 16992896);   //    16,384
    float*  EVB1   = (float*) (ws + 17009280);   //       512
    int*    bsum   = (int*)   (ws + 17009792);   //     1,664  (total ~17.0 MB)

    k_init       <<<260,  256, 0, stream>>>((int4*)count, evW, evb, W1, EVW1t, EVB1);
    k_pre        <<<2500, 256, 0, stream>>>(W2, dst, count, W2t);
    k_scan_bsum  <<<NB_SCAN, 256, 0, stream>>>(count, bsum);
    k_scan_final <<<NB_SCAN, 256, 0, stream>>>(count, bsum, rowptr);
    k_permute    <<<2500, 256, 0, stream>>>(dst, rowptr, cursor, perm);
    k_agg_gather <<<6250, 256, 0, stream>>>(ef, attn_W, perm, rowptr, agg, msum);
    k_mega       <<<782,  256, 0, stream>>>(agg, msum, EVW1t, EVB1, b1, W2t, b2, nf, out);
}

// Round 15
// 161.645 us; speedup vs baseline: 1.3267x; 1.1422x over previous
//
#include <hip/hip_runtime.h>
#include <cstddef>

#define NN 100000
#define NE 640000
#define NB_SCAN 391   // ceil(NN/256)
#define NTILE 1563    // ceil(NN/64)

typedef short  short8   __attribute__((ext_vector_type(8)));
typedef float  f32x4    __attribute__((ext_vector_type(4)));
typedef ushort ushort4v __attribute__((ext_vector_type(4)));

__device__ __forceinline__ short f2bf(float f) {   // RNE f32->bf16
    union { float f; unsigned u; } v; v.f = f;
    unsigned r = (v.u + 0x7fffu + ((v.u >> 16) & 1u)) >> 16;
    return (short)r;
}

// K-1 (merged): blocks 0..195 zero count+cursor; blocks 196..259 compute
// fused first-layer weights EVW1 = evW@W1 (bf16 [n][j]) and EVB1 = evb@W1.
__global__ __launch_bounds__(256) void k_init(
    int4* __restrict__ zp, const float* __restrict__ evW,
    const float* __restrict__ evb, const float* __restrict__ W1,
    ushort* __restrict__ EVW1t, float* __restrict__ EVB1)
{
    const int b = blockIdx.x;
    if (b < 196) {
        const int i = b * 256 + threadIdx.x;        // 50176 >= 50000
        if (i < 50000) zp[i] = make_int4(0, 0, 0, 0);
        return;
    }
    if (threadIdx.x >= 128) return;
    const int j = b - 196;        // 0..63
    const int n = threadIdx.x;    // 0..127
    float acc = 0.f;
    #pragma unroll 8
    for (int c = 0; c < 128; ++c)
        acc = fmaf(evW[j * 128 + c], W1[c * 128 + n], acc);
    EVW1t[n * 64 + j] = (ushort)f2bf(acc);
    if (j == 0) {
        float ab = 0.f;
        #pragma unroll 8
        for (int c = 0; c < 128; ++c)
            ab = fmaf(evb[c], W1[c * 128 + n], ab);
        EVB1[n] = ab;
    }
}

// K0 v2: STREAMING pass over ef (coalesced) -> edge scores + L3 warm-up.
// Also: W2 bf16-transpose + in-degree histogram. 16-lane group per 16 edges.
__global__ __launch_bounds__(256) void k_pre(
    const float* __restrict__ ef, const float* __restrict__ attn_W,
    const float* __restrict__ W2, const int* __restrict__ dst_idx,
    int* __restrict__ count, ushort* __restrict__ W2t,
    float* __restrict__ escore)
{
    const int t   = threadIdx.x;
    const int gid = blockIdx.x * 256 + t;
    if (gid < 16384) {
        const int n = gid >> 7, k = gid & 127;
        W2t[gid] = (ushort)f2bf(W2[k * 128 + n]);
    }

    const int sl = t & 15;
    const int e0 = blockIdx.x * 256 + (t >> 4) * 16;   // 16 edges per group

    float4 wl;   // mean_h attn_W rows 128+sl*4 .. +3
    {
        const float4 r0 = *reinterpret_cast<const float4*>(attn_W + (128 + sl * 4 + 0) * 4);
        const float4 r1 = *reinterpret_cast<const float4*>(attn_W + (128 + sl * 4 + 1) * 4);
        const float4 r2 = *reinterpret_cast<const float4*>(attn_W + (128 + sl * 4 + 2) * 4);
        const float4 r3 = *reinterpret_cast<const float4*>(attn_W + (128 + sl * 4 + 3) * 4);
        wl.x = 0.25f * (r0.x + r0.y + r0.z + r0.w);
        wl.y = 0.25f * (r1.x + r1.y + r1.z + r1.w);
        wl.z = 0.25f * (r2.x + r2.y + r2.z + r2.w);
        wl.w = 0.25f * (r3.x + r3.y + r3.z + r3.w);
    }

    float myscore = 0.f;
    #pragma unroll
    for (int b = 0; b < 2; ++b) {
        float4 v[8];
        #pragma unroll
        for (int j = 0; j < 8; ++j)
            v[j] = *reinterpret_cast<const float4*>(
                ef + (size_t)(e0 + b * 8 + j) * 64 + sl * 4);
        #pragma unroll
        for (int j = 0; j < 8; ++j) {
            float x = v[j].x * wl.x + v[j].y * wl.y + v[j].z * wl.z + v[j].w * wl.w;
            #pragma unroll
            for (int off = 8; off; off >>= 1) x += __shfl_xor(x, off, 16);
            if (sl == b * 8 + j) myscore = x;      // x broadcast across group
        }
    }
    escore[e0 + sl] = myscore;                     // coalesced 64B per group
    atomicAdd(&count[dst_idx[e0 + sl]], 1);        // coalesced dst load
}

// Scan A: per-block sums
__global__ __launch_bounds__(256) void k_scan_bsum(
    const int* __restrict__ count, int* __restrict__ bsum)
{
    __shared__ int s[256];
    const int t = threadIdx.x, i = blockIdx.x * 256 + t;
    s[t] = (i < NN) ? count[i] : 0;
    __syncthreads();
    for (int off = 128; off; off >>= 1) { if (t < off) s[t] += s[t + off]; __syncthreads(); }
    if (t == 0) bsum[blockIdx.x] = s[0];
}

// Scan B (merged): block prefix over bsum + in-block exclusive scan -> rowptr
__global__ __launch_bounds__(256) void k_scan_final(
    const int* __restrict__ count, const int* __restrict__ bsum,
    int* __restrict__ rowptr)
{
    __shared__ int s[256];
    __shared__ int red[4];
    const int t = threadIdx.x, i = blockIdx.x * 256 + t;
    const int v = (i < NN) ? count[i] : 0;
    s[t] = v;

    int part = 0;
    for (int b = t; b < blockIdx.x; b += 256) part += bsum[b];
    #pragma unroll
    for (int off = 32; off; off >>= 1) part += __shfl_xor(part, off);
    if ((t & 63) == 0) red[t >> 6] = part;
    __syncthreads();
    const int boff = red[0] + red[1] + red[2] + red[3];

    for (int off = 1; off < 256; off <<= 1) {
        const int x = (t >= off) ? s[t - off] : 0;
        __syncthreads();
        s[t] += x;
        __syncthreads();
    }
    if (i < NN) rowptr[i] = boff + s[t] - v;
    if (blockIdx.x == NB_SCAN - 1 && t == 255) rowptr[NN] = boff + s[255];
}

// K2: build permutation grouping edges by dst (CSR)
__global__ __launch_bounds__(256) void k_permute(
    const int* __restrict__ dst_idx, const int* __restrict__ rowptr,
    int* cursor, int* __restrict__ perm)
{
    const int e = blockIdx.x * 256 + threadIdx.x;     // grid 2500 exact
    const int dd = dst_idx[e];
    perm[rowptr[dd] + atomicAdd(&cursor[dd], 1)] = e;
}

// K3 v3: gather (ef now L3-warm from k_pre; scores precomputed -> no shfl
// reduce on the hot path) + online segment softmax + aggregation.
__global__ __launch_bounds__(256, 8) void k_agg_gather(
    const float* __restrict__ ef, const float* __restrict__ escore,
    const int* __restrict__ perm, const int* __restrict__ rowptr,
    ushort* __restrict__ agg, float* __restrict__ msum)
{
    const int t  = threadIdx.x;
    const int sl = t & 15;
    const int n  = blockIdx.x * 16 + (t >> 4);   // grid 6250 -> exact
    const int beg = rowptr[n], end = rowptr[n + 1];

    float m  = -3.0e38f;
    float se = 0.f;
    f32x4 acc = {0.f, 0.f, 0.f, 0.f};

    for (int i = beg; i < end; i += 6) {
        int pe[6];
        #pragma unroll
        for (int j = 0; j < 6; ++j)
            pe[j] = perm[(i + j < end) ? (i + j) : beg];
        float sraw[6];
        #pragma unroll
        for (int j = 0; j < 6; ++j)
            sraw[j] = escore[pe[j]];
        float4 v[6];
        #pragma unroll
        for (int j = 0; j < 6; ++j)
            v[j] = *reinterpret_cast<const float4*>(ef + (size_t)pe[j] * 64 + sl * 4);
        float sc[6];
        #pragma unroll
        for (int j = 0; j < 6; ++j)
            sc[j] = (i + j < end) ? sraw[j] : -3.0e38f;
        float bm = m;
        #pragma unroll
        for (int j = 0; j < 6; ++j) bm = fmaxf(bm, sc[j]);
        const float r = __expf(m - bm);
        acc[0] *= r; acc[1] *= r; acc[2] *= r; acc[3] *= r; se *= r;
        m = bm;
        #pragma unroll
        for (int j = 0; j < 6; ++j) {
            const float w = __expf(sc[j] - m);
            acc[0] = fmaf(w, v[j].x, acc[0]);
            acc[1] = fmaf(w, v[j].y, acc[1]);
            acc[2] = fmaf(w, v[j].z, acc[2]);
            acc[3] = fmaf(w, v[j].w, acc[3]);
            se += w;
        }
    }

    ushort4v o;
    o[0] = (ushort)f2bf(acc[0]); o[1] = (ushort)f2bf(acc[1]);
    o[2] = (ushort)f2bf(acc[2]); o[3] = (ushort)f2bf(acc[3]);
    *reinterpret_cast<ushort4v*>(agg + (size_t)n * 64 + sl * 4) = o;
    if (sl == 0) msum[n] = se;
}

// K5 (R12 version -- best measured: 31 us, weights in LDS, 2 blocks/CU).
__global__ __launch_bounds__(256, 2) void k_mega(
    const ushort* __restrict__ agg, const float* __restrict__ msum,
    const ushort* __restrict__ EVW1t, const float* __restrict__ EVB1,
    const float* __restrict__ b1, const ushort* __restrict__ W2t,
    const float* __restrict__ b2, const float* __restrict__ nf,
    float* __restrict__ out)
{
    __shared__ ushort wev[128 * 64];     // 16 KB EVW1 rows, swizzled
    __shared__ ushort ww2[128 * 128];    // 32 KB W2 rows, swizzled
    __shared__ ushort tl[4][16][136];    // 17 KB per-wave h1 staging

    const int tid  = threadIdx.x;
    const int wid  = tid >> 6;
    const int lane = tid & 63;
    const int r    = lane & 15;
    const int g    = lane >> 4;

    for (int c = tid; c < 1024; c += 256) {        // EVW1: 1024 x short8
        const int n = c >> 3, k8 = c & 7;
        *reinterpret_cast<short8*>(&wev[n * 64 + ((k8 ^ (n & 7)) * 8)]) =
            *reinterpret_cast<const short8*>(EVW1t + n * 64 + k8 * 8);
    }
    for (int c = tid; c < 2048; c += 256) {        // W2: 2048 x short8
        const int n = c >> 4, k8 = c & 15;
        *reinterpret_cast<short8*>(&ww2[n * 128 + ((k8 ^ (n & 7)) * 8)]) =
            *reinterpret_cast<const short8*>(W2t + n * 128 + k8 * 8);
    }
    __syncthreads();

    float evb1c[8], b1c[8], b2c[8];
    #pragma unroll
    for (int nt = 0; nt < 8; ++nt) {
        evb1c[nt] = EVB1[nt * 16 + r];
        b1c[nt]   = b1[nt * 16 + r];
        b2c[nt]   = b2[nt * 16 + r];
    }

    for (int bt = blockIdx.x; bt < NTILE; bt += gridDim.x) {
        const int n0 = bt * 64 + wid * 16;
        if (n0 >= NN) continue;                    // no syncs in loop -> safe

        const short8 aev0 = *reinterpret_cast<const short8*>(agg + (size_t)(n0 + r) * 64 + g * 8);
        const short8 aev1 = *reinterpret_cast<const short8*>(agg + (size_t)(n0 + r) * 64 + 32 + g * 8);
        float cf[4], cb[4];
        #pragma unroll
        for (int i = 0; i < 4; ++i) {
            const float s = msum[n0 + g * 4 + i];
            const float c = 1.f / (s + 1e-6f);
            cf[i] = c; cb[i] = s * c;
        }

        #pragma unroll
        for (int nt = 0; nt < 8; ++nt) {
            const int row = nt * 16 + r;
            const short8 w0 = *reinterpret_cast<const short8*>(
                &wev[row * 64 + (((0 + g) ^ (r & 7)) * 8)]);
            const short8 w1 = *reinterpret_cast<const short8*>(
                &wev[row * 64 + (((4 + g) ^ (r & 7)) * 8)]);
            f32x4 acc = {0.f, 0.f, 0.f, 0.f};
            acc = __builtin_amdgcn_mfma_f32_16x16x32_bf16(aev0, w0, acc, 0, 0, 0);
            acc = __builtin_amdgcn_mfma_f32_16x16x32_bf16(aev1, w1, acc, 0, 0, 0);
            #pragma unroll
            for (int i = 0; i < 4; ++i) {
                const float h = fmaxf(cf[i] * acc[i] + cb[i] * evb1c[nt] + b1c[nt], 0.f);
                tl[wid][g * 4 + i][nt * 16 + r] = (ushort)f2bf(h);
            }
        }
        asm volatile("s_waitcnt lgkmcnt(0)" ::: "memory");   // h1 writes landed

        short8 a2[4];
        #pragma unroll
        for (int t = 0; t < 4; ++t)
            a2[t] = *reinterpret_cast<const short8*>(&tl[wid][r][t * 32 + g * 8]);
        asm volatile("s_waitcnt lgkmcnt(0)" ::: "memory");   // reads done before overwrite

        #pragma unroll
        for (int nt = 0; nt < 8; ++nt) {
            f32x4 acc = {0.f, 0.f, 0.f, 0.f};
            #pragma unroll
            for (int t = 0; t < 4; ++t) {
                const short8 w = *reinterpret_cast<const short8*>(
                    &ww2[(nt * 16 + r) * 128 + (((t * 4 + g) ^ (r & 7)) * 8)]);
                acc = __builtin_amdgcn_mfma_f32_16x16x32_bf16(a2[t], w, acc, 0, 0, 0);
            }
            #pragma unroll
            for (int i = 0; i < 4; ++i) {
                const size_t idx = (size_t)(n0 + g * 4 + i) * 128 + nt * 16 + r;
                out[idx] = nf[idx] + acc[i] + b2c[nt];
            }
        }
    }
}

extern "C" void kernel_launch(void* const* d_in, const int* in_sizes, int n_in,
                              void* d_out, int out_size, void* d_ws, size_t ws_size,
                              hipStream_t stream)
{
    const float* nf     = (const float*)d_in[0];
    const float* ef     = (const float*)d_in[1];
    const float* attn_W = (const float*)d_in[2];
    const float* evW    = (const float*)d_in[4];
    const float* evb    = (const float*)d_in[5];
    const float* W1     = (const float*)d_in[6];
    const float* b1     = (const float*)d_in[7];
    const float* W2     = (const float*)d_in[8];
    const float* b2     = (const float*)d_in[9];
    const int*   eidx   = (const int*)d_in[10];
    const int*   dst    = eidx + NE;
    float* out = (float*)d_out;

    char* ws = (char*)d_ws;
    int*    count  = (int*)   (ws + 0);          //   400,000 } contiguous:
    int*    cursor = (int*)   (ws + 400000);     //   400,000 } zeroed by k_init
    int*    rowptr = (int*)   (ws + 800000);     //   400,004 (pad -> 1,200,128)
    float*  msum   = (float*) (ws + 1200128);    //   400,000
    int*    perm   = (int*)   (ws + 1600128);    // 2,560,000
    ushort* agg    = (ushort*)(ws + 4160128);    // 12,800,000
    ushort* W2t    = (ushort*)(ws + 16960128);   //    32,768
    ushort* EVW1t  = (ushort*)(ws + 16992896);   //    16,384
    float*  EVB1   = (float*) (ws + 17009280);   //       512
    int*    bsum   = (int*)   (ws + 17009792);   //     1,664
    float*  escore = (float*) (ws + 17011456);   // 2,560,000  (total ~19.6 MB)

    k_init       <<<260,  256, 0, stream>>>((int4*)count, evW, evb, W1, EVW1t, EVB1);
    k_pre        <<<2500, 256, 0, stream>>>(ef, attn_W, W2, dst, count, W2t, escore);
    k_scan_bsum  <<<NB_SCAN, 256, 0, stream>>>(count, bsum);
    k_scan_final <<<NB_SCAN, 256, 0, stream>>>(count, bsum, rowptr);
    k_permute    <<<2500, 256, 0, stream>>>(dst, rowptr, cursor, perm);
    k_agg_gather <<<6250, 256, 0, stream>>>(ef, escore, perm, rowptr, agg, msum);
    k_mega       <<<521,  256, 0, stream>>>(agg, msum, EVW1t, EVB1, b1, W2t, b2, nf, out);
}

// Round 16
// 142.923 us; speedup vs baseline: 1.5005x; 1.1310x over previous
//
#include <hip/hip_runtime.h>
#include <cstddef>

#define NN 100000
#define NE 640000
#define NB_SCAN 391   // ceil(NN/256)
#define NTILE 1563    // ceil(NN/64) == 3 * 521
#define MGRID 521

typedef short  short8   __attribute__((ext_vector_type(8)));
typedef float  f32x4    __attribute__((ext_vector_type(4)));
typedef ushort ushort4v __attribute__((ext_vector_type(4)));

__device__ __forceinline__ short f2bf(float f) {   // RNE f32->bf16
    union { float f; unsigned u; } v; v.f = f;
    unsigned r = (v.u + 0x7fffu + ((v.u >> 16) & 1u)) >> 16;
    return (short)r;
}

// K-1 (merged): blocks 0..195 zero count+cursor; blocks 196..259 compute
// fused first-layer weights EVW1 = evW@W1 (bf16 [n][j]) and EVB1 = evb@W1.
__global__ __launch_bounds__(256) void k_init(
    int4* __restrict__ zp, const float* __restrict__ evW,
    const float* __restrict__ evb, const float* __restrict__ W1,
    ushort* __restrict__ EVW1t, float* __restrict__ EVB1)
{
    const int b = blockIdx.x;
    if (b < 196) {
        const int i = b * 256 + threadIdx.x;        // 50176 >= 50000
        if (i < 50000) zp[i] = make_int4(0, 0, 0, 0);
        return;
    }
    if (threadIdx.x >= 128) return;
    const int j = b - 196;        // 0..63
    const int n = threadIdx.x;    // 0..127
    float acc = 0.f;
    #pragma unroll 8
    for (int c = 0; c < 128; ++c)
        acc = fmaf(evW[j * 128 + c], W1[c * 128 + n], acc);
    EVW1t[n * 64 + j] = (ushort)f2bf(acc);
    if (j == 0) {
        float ab = 0.f;
        #pragma unroll 8
        for (int c = 0; c < 128; ++c)
            ab = fmaf(evb[c], W1[c * 128 + n], ab);
        EVB1[n] = ab;
    }
}

// K0: W2 bf16-transpose + in-degree histogram (R12 version).
__global__ __launch_bounds__(256) void k_pre(
    const float* __restrict__ W2, const int* __restrict__ dst_idx,
    int* __restrict__ count, ushort* __restrict__ W2t)
{
    const int gid = blockIdx.x * 256 + threadIdx.x;   // grid 2500 -> gid < NE
    if (gid < 16384) {
        const int n = gid >> 7, k = gid & 127;
        W2t[gid] = (ushort)f2bf(W2[k * 128 + n]);
    }
    atomicAdd(&count[dst_idx[gid]], 1);               // 2500*256 == NE exactly
}

// Scan A: per-block sums
__global__ __launch_bounds__(256) void k_scan_bsum(
    const int* __restrict__ count, int* __restrict__ bsum)
{
    __shared__ int s[256];
    const int t = threadIdx.x, i = blockIdx.x * 256 + t;
    s[t] = (i < NN) ? count[i] : 0;
    __syncthreads();
    for (int off = 128; off; off >>= 1) { if (t < off) s[t] += s[t + off]; __syncthreads(); }
    if (t == 0) bsum[blockIdx.x] = s[0];
}

// Scan B (merged): block prefix over bsum + in-block exclusive scan -> rowptr
__global__ __launch_bounds__(256) void k_scan_final(
    const int* __restrict__ count, const int* __restrict__ bsum,
    int* __restrict__ rowptr)
{
    __shared__ int s[256];
    __shared__ int red[4];
    const int t = threadIdx.x, i = blockIdx.x * 256 + t;
    const int v = (i < NN) ? count[i] : 0;
    s[t] = v;

    int part = 0;
    for (int b = t; b < blockIdx.x; b += 256) part += bsum[b];
    #pragma unroll
    for (int off = 32; off; off >>= 1) part += __shfl_xor(part, off);
    if ((t & 63) == 0) red[t >> 6] = part;
    __syncthreads();
    const int boff = red[0] + red[1] + red[2] + red[3];

    for (int off = 1; off < 256; off <<= 1) {
        const int x = (t >= off) ? s[t - off] : 0;
        __syncthreads();
        s[t] += x;
        __syncthreads();
    }
    if (i < NN) rowptr[i] = boff + s[t] - v;
    if (blockIdx.x == NB_SCAN - 1 && t == 255) rowptr[NN] = boff + s[255];
}

// K2: build permutation grouping edges by dst (CSR)
__global__ __launch_bounds__(256) void k_permute(
    const int* __restrict__ dst_idx, const int* __restrict__ rowptr,
    int* cursor, int* __restrict__ perm)
{
    const int e = blockIdx.x * 256 + threadIdx.x;     // grid 2500 exact
    const int dd = dst_idx[e];
    perm[rowptr[dd] + atomicAdd(&cursor[dd], 1)] = e;
}

// K3: gather + online segment softmax + aggregation (R12 version — measured
// near the random-256B-gather HBM service limit).
__global__ __launch_bounds__(256, 8) void k_agg_gather(
    const float* __restrict__ ef, const float* __restrict__ attn_W,
    const int* __restrict__ perm, const int* __restrict__ rowptr,
    ushort* __restrict__ agg, float* __restrict__ msum)
{
    const int t  = threadIdx.x;
    const int sl = t & 15;
    const int n  = blockIdx.x * 16 + (t >> 4);   // grid 6250 -> exact
    const int beg = rowptr[n], end = rowptr[n + 1];

    float4 wl;   // mean_h attn_W rows 128+sl*4 .. +3
    {
        const float4 r0 = *reinterpret_cast<const float4*>(attn_W + (128 + sl * 4 + 0) * 4);
        const float4 r1 = *reinterpret_cast<const float4*>(attn_W + (128 + sl * 4 + 1) * 4);
        const float4 r2 = *reinterpret_cast<const float4*>(attn_W + (128 + sl * 4 + 2) * 4);
        const float4 r3 = *reinterpret_cast<const float4*>(attn_W + (128 + sl * 4 + 3) * 4);
        wl.x = 0.25f * (r0.x + r0.y + r0.z + r0.w);
        wl.y = 0.25f * (r1.x + r1.y + r1.z + r1.w);
        wl.z = 0.25f * (r2.x + r2.y + r2.z + r2.w);
        wl.w = 0.25f * (r3.x + r3.y + r3.z + r3.w);
    }

    float m  = -3.0e38f;
    float se = 0.f;
    f32x4 acc = {0.f, 0.f, 0.f, 0.f};

    for (int i = beg; i < end; i += 6) {
        int pe[6];
        #pragma unroll
        for (int j = 0; j < 6; ++j)
            pe[j] = perm[(i + j < end) ? (i + j) : beg];
        float4 v[6];
        #pragma unroll
        for (int j = 0; j < 6; ++j)
            v[j] = *reinterpret_cast<const float4*>(ef + (size_t)pe[j] * 64 + sl * 4);
        float sc[6];
        #pragma unroll
        for (int j = 0; j < 6; ++j) {
            float x = v[j].x * wl.x + v[j].y * wl.y + v[j].z * wl.z + v[j].w * wl.w;
            #pragma unroll
            for (int off = 8; off; off >>= 1) x += __shfl_xor(x, off, 16);
            sc[j] = (i + j < end) ? x : -3.0e38f;
        }
        float bm = m;
        #pragma unroll
        for (int j = 0; j < 6; ++j) bm = fmaxf(bm, sc[j]);
        const float r = __expf(m - bm);
        acc[0] *= r; acc[1] *= r; acc[2] *= r; acc[3] *= r; se *= r;
        m = bm;
        #pragma unroll
        for (int j = 0; j < 6; ++j) {
            const float w = __expf(sc[j] - m);
            acc[0] = fmaf(w, v[j].x, acc[0]);
            acc[1] = fmaf(w, v[j].y, acc[1]);
            acc[2] = fmaf(w, v[j].z, acc[2]);
            acc[3] = fmaf(w, v[j].w, acc[3]);
            se += w;
        }
    }

    ushort4v o;
    o[0] = (ushort)f2bf(acc[0]); o[1] = (ushort)f2bf(acc[1]);
    o[2] = (ushort)f2bf(acc[2]); o[3] = (ushort)f2bf(acc[3]);
    *reinterpret_cast<ushort4v*>(agg + (size_t)n * 64 + sl * 4) = o;
    if (sl == 0) msum[n] = se;
}

// ---- K5 v7: software-pipelined tiles (register double-buffer prefetch) ----
struct TileRegs {
    short8 a0, a1;
    float cf0, cf1, cf2, cf3;
    float cb0, cb1, cb2, cb3;
    float nfv[32];                 // residuals, constant-indexed (unrolled)
};

__device__ __forceinline__ void tl_load(
    TileRegs& T, const ushort* __restrict__ agg, const float* __restrict__ msum,
    const float* __restrict__ nf, int n0, int r, int g)
{
    T.a0 = *reinterpret_cast<const short8*>(agg + (size_t)(n0 + r) * 64 + g * 8);
    T.a1 = *reinterpret_cast<const short8*>(agg + (size_t)(n0 + r) * 64 + 32 + g * 8);
    const float s0 = msum[n0 + g * 4 + 0];
    const float s1 = msum[n0 + g * 4 + 1];
    const float s2 = msum[n0 + g * 4 + 2];
    const float s3 = msum[n0 + g * 4 + 3];
    T.cf0 = 1.f / (s0 + 1e-6f); T.cb0 = s0 * T.cf0;
    T.cf1 = 1.f / (s1 + 1e-6f); T.cb1 = s1 * T.cf1;
    T.cf2 = 1.f / (s2 + 1e-6f); T.cb2 = s2 * T.cf2;
    T.cf3 = 1.f / (s3 + 1e-6f); T.cb3 = s3 * T.cf3;
    #pragma unroll
    for (int nt = 0; nt < 8; ++nt)
        #pragma unroll
        for (int i = 0; i < 4; ++i)
            T.nfv[nt * 4 + i] = nf[(size_t)(n0 + g * 4 + i) * 128 + nt * 16 + r];
}

__device__ __forceinline__ void tl_compute(
    const TileRegs& T, const ushort* __restrict__ wev,
    const ushort* __restrict__ ww2, ushort* __restrict__ tlw,
    const float* __restrict__ evb1c, const float* __restrict__ b1c,
    const float* __restrict__ b2c, float* __restrict__ out,
    int n0, int r, int g)
{
    const float cf[4] = {T.cf0, T.cf1, T.cf2, T.cf3};
    const float cb[4] = {T.cb0, T.cb1, T.cb2, T.cb3};

    // phase A: fused ev+L1 GEMM (K=64) + relu -> h1 (bf16, wave-private LDS)
    #pragma unroll
    for (int nt = 0; nt < 8; ++nt) {
        const int row = nt * 16 + r;
        const short8 w0 = *reinterpret_cast<const short8*>(
            &wev[row * 64 + (((0 + g) ^ (r & 7)) * 8)]);
        const short8 w1 = *reinterpret_cast<const short8*>(
            &wev[row * 64 + (((4 + g) ^ (r & 7)) * 8)]);
        f32x4 acc = {0.f, 0.f, 0.f, 0.f};
        acc = __builtin_amdgcn_mfma_f32_16x16x32_bf16(T.a0, w0, acc, 0, 0, 0);
        acc = __builtin_amdgcn_mfma_f32_16x16x32_bf16(T.a1, w1, acc, 0, 0, 0);
        #pragma unroll
        for (int i = 0; i < 4; ++i) {
            const float h = fmaxf(cf[i] * acc[i] + cb[i] * evb1c[nt] + b1c[nt], 0.f);
            tlw[(g * 4 + i) * 136 + nt * 16 + r] = (ushort)f2bf(h);
        }
    }
    asm volatile("s_waitcnt lgkmcnt(0)" ::: "memory");   // h1 writes landed

    short8 a2[4];
    #pragma unroll
    for (int t = 0; t < 4; ++t)
        a2[t] = *reinterpret_cast<const short8*>(&tlw[r * 136 + t * 32 + g * 8]);
    asm volatile("s_waitcnt lgkmcnt(0)" ::: "memory");   // reads done before overwrite

    // phase B: GEMM2 + bias + residual (nf prefetched in T.nfv)
    #pragma unroll
    for (int nt = 0; nt < 8; ++nt) {
        f32x4 acc = {0.f, 0.f, 0.f, 0.f};
        #pragma unroll
        for (int t = 0; t < 4; ++t) {
            const short8 w = *reinterpret_cast<const short8*>(
                &ww2[(nt * 16 + r) * 128 + (((t * 4 + g) ^ (r & 7)) * 8)]);
            acc = __builtin_amdgcn_mfma_f32_16x16x32_bf16(a2[t], w, acc, 0, 0, 0);
        }
        #pragma unroll
        for (int i = 0; i < 4; ++i) {
            const size_t idx = (size_t)(n0 + g * 4 + i) * 128 + nt * 16 + r;
            out[idx] = T.nfv[nt * 4 + i] + acc[i] + b2c[nt];
        }
    }
}

__global__ __launch_bounds__(256, 2) void k_mega(
    const ushort* __restrict__ agg, const float* __restrict__ msum,
    const ushort* __restrict__ EVW1t, const float* __restrict__ EVB1,
    const float* __restrict__ b1, const ushort* __restrict__ W2t,
    const float* __restrict__ b2, const float* __restrict__ nf,
    float* __restrict__ out)
{
    __shared__ ushort wev[128 * 64];     // 16 KB EVW1 rows, swizzled
    __shared__ ushort ww2[128 * 128];    // 32 KB W2 rows, swizzled
    __shared__ ushort tl[4][16][136];    // 17 KB per-wave h1 staging

    const int tid  = threadIdx.x;
    const int wid  = tid >> 6;
    const int lane = tid & 63;
    const int r    = lane & 15;
    const int g    = lane >> 4;

    const int bt0 = blockIdx.x;          // grid = 521; tiles bt0, +521, +1042
    const int bt1 = bt0 + MGRID;
    const int bt2 = bt0 + 2 * MGRID;
    const int n00 = bt0 * 64 + wid * 16;
    const int n01 = bt1 * 64 + wid * 16;
    const int n02 = bt2 * 64 + wid * 16;
    const bool a0 = n00 < NN, a1 = n01 < NN, a2v = n02 < NN;

    // tile-0 loads FIRST: latency hides under weight staging + barrier
    TileRegs tA, tB, tC;
    if (a0) tl_load(tA, agg, msum, nf, n00, r, g);

    for (int c = tid; c < 1024; c += 256) {        // EVW1: 1024 x short8
        const int n = c >> 3, k8 = c & 7;
        *reinterpret_cast<short8*>(&wev[n * 64 + ((k8 ^ (n & 7)) * 8)]) =
            *reinterpret_cast<const short8*>(EVW1t + n * 64 + k8 * 8);
    }
    for (int c = tid; c < 2048; c += 256) {        // W2: 2048 x short8
        const int n = c >> 4, k8 = c & 15;
        *reinterpret_cast<short8*>(&ww2[n * 128 + ((k8 ^ (n & 7)) * 8)]) =
            *reinterpret_cast<const short8*>(W2t + n * 128 + k8 * 8);
    }
    __syncthreads();

    float evb1c[8], b1c[8], b2c[8];
    #pragma unroll
    for (int nt = 0; nt < 8; ++nt) {
        evb1c[nt] = EVB1[nt * 16 + r];
        b1c[nt]   = b1[nt * 16 + r];
        b2c[nt]   = b2[nt * 16 + r];
    }

    ushort* tlw = &tl[wid][0][0];

    if (a1) tl_load(tB, agg, msum, nf, n01, r, g);       // prefetch tile 1
    if (a0) tl_compute(tA, wev, ww2, tlw, evb1c, b1c, b2c, out, n00, r, g);
    if (a2v) tl_load(tC, agg, msum, nf, n02, r, g);      // prefetch tile 2
    if (a1) tl_compute(tB, wev, ww2, tlw, evb1c, b1c, b2c, out, n01, r, g);
    if (a2v) tl_compute(tC, wev, ww2, tlw, evb1c, b1c, b2c, out, n02, r, g);
}

extern "C" void kernel_launch(void* const* d_in, const int* in_sizes, int n_in,
                              void* d_out, int out_size, void* d_ws, size_t ws_size,
                              hipStream_t stream)
{
    const float* nf     = (const float*)d_in[0];
    const float* ef     = (const float*)d_in[1];
    const float* attn_W = (const float*)d_in[2];
    const float* evW    = (const float*)d_in[4];
    const float* evb    = (const float*)d_in[5];
    const float* W1     = (const float*)d_in[6];
    const float* b1     = (const float*)d_in[7];
    const float* W2     = (const float*)d_in[8];
    const float* b2     = (const float*)d_in[9];
    const int*   eidx   = (const int*)d_in[10];
    const int*   dst    = eidx + NE;
    float* out = (float*)d_out;

    char* ws = (char*)d_ws;
    int*    count  = (int*)   (ws + 0);          //   400,000 } contiguous:
    int*    cursor = (int*)   (ws + 400000);     //   400,000 } zeroed by k_init
    int*    rowptr = (int*)   (ws + 800000);     //   400,004 (pad -> 1,200,128)
    float*  msum   = (float*) (ws + 1200128);    //   400,000
    int*    perm   = (int*)   (ws + 1600128);    // 2,560,000
    ushort* agg    = (ushort*)(ws + 4160128);    // 12,800,000
    ushort* W2t    = (ushort*)(ws + 16960128);   //    32,768
    ushort* EVW1t  = (ushort*)(ws + 16992896);   //    16,384
    float*  EVB1   = (float*) (ws + 17009280);   //       512
    int*    bsum   = (int*)   (ws + 17009792);   //     1,664  (total ~17.0 MB)

    k_init       <<<260,  256, 0, stream>>>((int4*)count, evW, evb, W1, EVW1t, EVB1);
    k_pre        <<<2500, 256, 0, stream>>>(W2, dst, count, W2t);
    k_scan_bsum  <<<NB_SCAN, 256, 0, stream>>>(count, bsum);
    k_scan_final <<<NB_SCAN, 256, 0, stream>>>(count, bsum, rowptr);
    k_permute    <<<2500, 256, 0, stream>>>(dst, rowptr, cursor, perm);
    k_agg_gather <<<6250, 256, 0, stream>>>(ef, attn_W, perm, rowptr, agg, msum);
    k_mega       <<<MGRID, 256, 0, stream>>>(agg, msum, EVW1t, EVB1, b1, W2t, b2, nf, out);
}